// Round 14
// baseline (289.519 us; speedup 1.0000x reference)
//
#include <hip/hip_runtime.h>
#include <math.h>

#define DI 512
#define DM 256
#define LSEQ 1024
#define BB 4
#define NST 64
#define ROWS (BB*LSEQ)   // 4096
#define NC 16            // chunks per sequence
#define CL 64            // chunk length

typedef __bf16 bf16x8 __attribute__((ext_vector_type(8)));
typedef __bf16 bf16x4 __attribute__((ext_vector_type(4)));
typedef float f32x4 __attribute__((ext_vector_type(4)));
typedef unsigned short u16;
typedef u16 u16x8 __attribute__((ext_vector_type(8)));
typedef int i32x2 __attribute__((ext_vector_type(2)));

__device__ __forceinline__ float siluf(float x) { return x / (1.f + __expf(-x)); }
__device__ __forceinline__ float softplusf(float x) { return (x > 20.f) ? x : log1pf(__expf(x)); }
__device__ __forceinline__ float rlane(float v, int l) {
    return __int_as_float(__builtin_amdgcn_readlane(__float_as_int(v), l));
}
__device__ __forceinline__ float fexp2(float x) {
#if __has_builtin(__builtin_amdgcn_exp2f)
    return __builtin_amdgcn_exp2f(x);
#else
    return __expf(x * 0.69314718056f);
#endif
}
__device__ __forceinline__ float bf2f(u16 u) {
    return __uint_as_float(((unsigned)u) << 16);
}
template<int PAT>
__device__ __forceinline__ float fswz(float v) {
    return __int_as_float(__builtin_amdgcn_ds_swizzle(__float_as_int(v), PAT));
}

// pairing-tree reduction: sums s[0..7] (each across all 64 lanes).
// Result: lane L holds total of s[L>>3].
__device__ __forceinline__ float tree8(const float (&s)[8], int lane) {
    const bool b4 = (lane & 16) != 0;
    const bool b3 = (lane & 8) != 0;
    float r[4];
#if __has_builtin(__builtin_amdgcn_permlane32_swap)
    #pragma unroll
    for (int i = 0; i < 4; ++i) {
        i32x2 pr = __builtin_amdgcn_permlane32_swap(
            __float_as_int(s[i]), __float_as_int(s[i+4]), false, false);
        r[i] = __int_as_float(pr[0]) + __int_as_float(pr[1]);
    }
#else
    const bool b5 = (lane & 32) != 0;
    #pragma unroll
    for (int i = 0; i < 4; ++i) {
        float u = b5 ? s[i+4] : s[i];
        float w = b5 ? s[i]   : s[i+4];
        r[i] = u + __shfl_xor(w, 32, 64);
    }
#endif
    float q[2];
    #pragma unroll
    for (int i = 0; i < 2; ++i) {
        float u = b4 ? r[i+2] : r[i];
        float w = b4 ? r[i]   : r[i+2];
        q[i] = u + fswz<0x401F>(w);   // xor 16
    }
    float u = b3 ? q[1] : q[0];
    float w = b3 ? q[0] : q[1];
    float p = u + fswz<0x201F>(w);    // xor 8
    p += fswz<0x101F>(p);             // xor 4
    p += fswz<0x081F>(p);             // xor 2
    p += fswz<0x041F>(p);             // xor 1
    return p;
}

// ------------- merged float -> bf16 convert (3 weight arrays) --------
__global__ __launch_bounds__(256) void f2bf3(
    const float* __restrict__ a, __bf16* __restrict__ da, int na,
    const float* __restrict__ b, __bf16* __restrict__ db, int nb,
    const float* __restrict__ c, __bf16* __restrict__ dc, int nc)
{
    int i = (blockIdx.x * 256 + threadIdx.x) * 4;
    const float* src; __bf16* dst;
    if (i < na) { src = a + i; dst = da + i; }
    else {
        i -= na;
        if (i < nb) { src = b + i; dst = db + i; }
        else {
            i -= nb;
            if (i >= nc) return;
            src = c + i; dst = dc + i;
        }
    }
    float4 v = *(const float4*)src;
    bf16x4 o;
    o[0] = (__bf16)v.x; o[1] = (__bf16)v.y; o[2] = (__bf16)v.z; o[3] = (__bf16)v.w;
    *(bf16x4*)dst = o;
}

// ---------------- LayerNorm: one wave per row of 256, bf16 out ------
__global__ __launch_bounds__(256) void ln_kernel(
    const float* __restrict__ x, const float* __restrict__ g,
    const float* __restrict__ b, __bf16* __restrict__ xn)
{
    int lane = threadIdx.x & 63;
    int row = blockIdx.x * 4 + (threadIdx.x >> 6);
    const float4* xr = (const float4*)(x + (size_t)row * DM);
    float4 v = xr[lane];
    float s = v.x + v.y + v.z + v.w;
    #pragma unroll
    for (int o = 32; o; o >>= 1) s += __shfl_xor(s, o, 64);
    float mu = s * (1.f / DM);
    float dx = v.x - mu, dy = v.y - mu, dz = v.z - mu, dw = v.w - mu;
    float q = dx*dx + dy*dy + dz*dz + dw*dw;
    #pragma unroll
    for (int o = 32; o; o >>= 1) q += __shfl_xor(q, o, 64);
    float inv = rsqrtf(q * (1.f / DM) + 1e-5f);
    float4 gv = ((const float4*)g)[lane];
    float4 bv = ((const float4*)b)[lane];
    bf16x4 o4;
    o4[0] = (__bf16)(dx * inv * gv.x + bv.x);
    o4[1] = (__bf16)(dy * inv * gv.y + bv.y);
    o4[2] = (__bf16)(dz * inv * gv.z + bv.z);
    o4[3] = (__bf16)(dw * inv * gv.w + bv.w);
    *(bf16x4*)(xn + (size_t)row * DM + lane * 4) = o4;
}

// ------------- bf16 MFMA GEMM: C[M,N] = A[M,K] @ W[N,K]^T -----------
// mode 0: fp32 store (col guard, ldc=N)
// mode 1: split at 512 -> C1b bf16 (ld 512) | C2b bf16 (ld 512)
// mode 2: fp32 store + res add (ldc=N)
template<int KK>
__global__ __launch_bounds__(256) void gemm_mfma(
    const __bf16* __restrict__ A, const __bf16* __restrict__ W,
    float* __restrict__ C, __bf16* __restrict__ C1b, __bf16* __restrict__ C2b,
    const float* __restrict__ res, int N, int mode)
{
    int wid = threadIdx.x >> 6, lane = threadIdx.x & 63;
    int wr = wid >> 1, wc = wid & 1;
    int bm = blockIdx.y * 64, bn = blockIdx.x * 64;
    int l15 = lane & 15, lk = (lane >> 4) * 8;
    const __bf16* Ap = A + (size_t)(bm + wr*32 + l15) * KK + lk;
    int wrow0 = bn + wc*32 + l15;
    int wrow1 = wrow0 + 16;
    if (wrow0 > N-1) wrow0 = N-1;
    if (wrow1 > N-1) wrow1 = N-1;
    const __bf16* Wp0 = W + (size_t)wrow0 * KK + lk;
    const __bf16* Wp1 = W + (size_t)wrow1 * KK + lk;
    f32x4 acc[2][2] = {};
    #pragma unroll 4
    for (int k0 = 0; k0 < KK; k0 += 32) {
        bf16x8 b0 = *(const bf16x8*)(Wp0 + k0);
        bf16x8 b1 = *(const bf16x8*)(Wp1 + k0);
        #pragma unroll
        for (int m = 0; m < 2; ++m) {
            bf16x8 a = *(const bf16x8*)(Ap + (size_t)m*16*KK + k0);
            acc[m][0] = __builtin_amdgcn_mfma_f32_16x16x32_bf16(a, b0, acc[m][0], 0, 0, 0);
            acc[m][1] = __builtin_amdgcn_mfma_f32_16x16x32_bf16(a, b1, acc[m][1], 0, 0, 0);
        }
    }
    int r4 = (lane >> 4) * 4;
    #pragma unroll
    for (int m = 0; m < 2; ++m) {
        int row = bm + wr*32 + m*16 + r4;
        #pragma unroll
        for (int n = 0; n < 2; ++n) {
            int col = bn + wc*32 + n*16 + l15;
            #pragma unroll
            for (int r = 0; r < 4; ++r) {
                float v = acc[m][n][r];
                int rr = row + r;
                if (mode == 0) {
                    if (col < N) C[(size_t)rr * N + col] = v;
                } else if (mode == 1) {
                    if (col < 512) C1b[(size_t)rr * 512 + col] = (__bf16)v;
                    else           C2b[(size_t)rr * 512 + col - 512] = (__bf16)v;
                } else {
                    C[(size_t)rr * N + col] = v + res[(size_t)rr * N + col];
                }
            }
        }
    }
}

// -------- fp32 tiled GEMM (dt projection, K=16) -> TRANSPOSED out ----
// writes CT[n][m] (ld ROWS) coalesced via LDS, fused softplus(+bias)
__global__ __launch_bounds__(256) void gemm_dt(
    const float* __restrict__ A, int lda,
    const float* __restrict__ W,
    float* __restrict__ CT, const float* __restrict__ aux)
{
    __shared__ float As[16][68];
    __shared__ float Ws[16][68];
    __shared__ float Ct[64][66];
    const int bm = blockIdx.y * 64;
    const int bn = blockIdx.x * 64;
    const int tid = threadIdx.x;
    const int tx = tid & 15;
    const int ty = tid >> 4;
    const int lr = tid >> 2;
    const int lc = (tid & 3) << 2;
    float acc[4][4] = {};
    {
        float4 av = *(const float4*)(A + (size_t)(bm + lr) * lda + lc);
        float4 wv = *(const float4*)(W + (size_t)(bn + lr) * 16 + lc);
        As[lc+0][lr] = av.x; As[lc+1][lr] = av.y; As[lc+2][lr] = av.z; As[lc+3][lr] = av.w;
        Ws[lc+0][lr] = wv.x; Ws[lc+1][lr] = wv.y; Ws[lc+2][lr] = wv.z; Ws[lc+3][lr] = wv.w;
        __syncthreads();
        #pragma unroll
        for (int k = 0; k < 16; ++k) {
            float a[4], w[4];
            #pragma unroll
            for (int i = 0; i < 4; ++i) a[i] = As[k][ty*4 + i];
            #pragma unroll
            for (int j = 0; j < 4; ++j) w[j] = Ws[k][tx*4 + j];
            #pragma unroll
            for (int i = 0; i < 4; ++i)
                #pragma unroll
                for (int j = 0; j < 4; ++j)
                    acc[i][j] = fmaf(a[i], w[j], acc[i][j]);
        }
    }
    // softplus + stage transposed in LDS
    #pragma unroll
    for (int j = 0; j < 4; ++j) {
        float bia = aux[bn + tx*4 + j];
        #pragma unroll
        for (int i = 0; i < 4; ++i)
            Ct[tx*4 + j][ty*4 + i] = softplusf(acc[i][j] + bia);
    }
    __syncthreads();
    // coalesced write: thread t -> row n=t>>2, m-chunk (t&3)*16
    {
        int n = tid >> 2;
        int mc = (tid & 3) * 16;
        float* dst = CT + (size_t)(bn + n) * ROWS + bm + mc;
        #pragma unroll
        for (int j4 = 0; j4 < 4; ++j4) {
            float4 v;
            v.x = Ct[n][mc + j4*4 + 0];
            v.y = Ct[n][mc + j4*4 + 1];
            v.z = Ct[n][mc + j4*4 + 2];
            v.w = Ct[n][mc + j4*4 + 3];
            *(float4*)(dst + j4*4) = v;
        }
    }
}

// --- fused: conv(k=4)+SiLU with dual-layout out, plus z transpose ----
// xm input is bf16 now.
__global__ __launch_bounds__(256) void conv_tr_kernel(
    const __bf16* __restrict__ xm, const float* __restrict__ cw,
    const float* __restrict__ cb, const u16* __restrict__ zin,
    __bf16* __restrict__ xcb, u16* __restrict__ xcT, u16* __restrict__ zT)
{
    __shared__ float xs[67][66];
    __shared__ u16 Tc[64][72];
    __shared__ u16 Tz[64][72];
    const int tid = threadIdx.x;
    const int row0 = blockIdx.y * 64;
    const int d0 = blockIdx.x * 64;
    // stage xm rows row0-3 .. row0+63 (67 rows x 64 d), bf16 -> fp32
    #pragma unroll
    for (int it = 0; it < 3; ++it) {
        int q = it * 256 + tid;       // chunk of 8 u16
        if (q < 67 * 8) {
            int rr = q >> 3;
            int cc = (q & 7) * 8;
            int g = row0 - 3 + rr;
            float f[8] = {0.f,0.f,0.f,0.f,0.f,0.f,0.f,0.f};
            if (g >= 0 && (g >> 10) == (row0 >> 10)) {
                u16x8 v = *(const u16x8*)((const u16*)xm + (size_t)g * DI + d0 + cc);
                #pragma unroll
                for (int j = 0; j < 8; ++j) f[j] = bf2f(v[j]);
            }
            #pragma unroll
            for (int j = 0; j < 8; ++j) xs[rr][cc + j] = f[j];
        }
    }
    const int r = tid >> 2;
    const int c0 = (tid & 3) * 16;
    {
        const u16* zp = zin + (size_t)(row0 + r) * DI + d0 + c0;
        *(u16x8*)&Tz[r][c0]     = *(const u16x8*)(zp);
        *(u16x8*)&Tz[r][c0 + 8] = *(const u16x8*)(zp + 8);
    }
    __syncthreads();
    {
        bf16x8 v0, v1;
        #pragma unroll
        for (int j = 0; j < 16; ++j) {
            int d = d0 + c0 + j;
            float acc = cb[d]
                + xs[r+0][c0+j] * cw[d*4+0]
                + xs[r+1][c0+j] * cw[d*4+1]
                + xs[r+2][c0+j] * cw[d*4+2]
                + xs[r+3][c0+j] * cw[d*4+3];
            __bf16 o = (__bf16)siluf(acc);
            if (j < 8) v0[j] = o; else v1[j-8] = o;
            Tc[r][c0+j] = *(const u16*)&o;
        }
        __bf16* op = xcb + (size_t)(row0 + r) * DI + d0 + c0;
        *(bf16x8*)(op)     = v0;
        *(bf16x8*)(op + 8) = v1;
    }
    __syncthreads();
    {
        u16x8 a0, a1, b0, b1;
        #pragma unroll
        for (int i = 0; i < 8; ++i) {
            a0[i] = Tc[c0+i][r];   a1[i] = Tc[c0+8+i][r];
            b0[i] = Tz[c0+i][r];   b1[i] = Tz[c0+8+i][r];
        }
        u16* oc = xcT + (size_t)(d0 + r) * ROWS + row0 + c0;
        u16* oz = zT  + (size_t)(d0 + r) * ROWS + row0 + c0;
        *(u16x8*)(oc)     = a0;
        *(u16x8*)(oc + 8) = a1;
        *(u16x8*)(oz)     = b0;
        *(u16x8*)(oz + 8) = b1;
    }
}

// ----- bf16 transpose tile 64x64: ld=ldi -> out ld=ldo (y only) -----
__global__ __launch_bounds__(256) void transpose_bf(
    const u16* __restrict__ in, u16* __restrict__ out, int ldi, int ldo)
{
    __shared__ u16 tile[64][72];
    int r = threadIdx.x >> 2;
    int c0 = (threadIdx.x & 3) * 16;
    const u16* ip = in + (size_t)(blockIdx.y*64 + r) * ldi + blockIdx.x*64 + c0;
    *(u16x8*)&tile[r][c0]     = *(const u16x8*)(ip);
    *(u16x8*)&tile[r][c0 + 8] = *(const u16x8*)(ip + 8);
    __syncthreads();
    u16* op = out + (size_t)(blockIdx.x*64 + r) * ldo + blockIdx.y*64 + c0;
    u16x8 v0, v1;
    #pragma unroll
    for (int i = 0; i < 8; ++i) { v0[i] = tile[c0+i][r]; v1[i] = tile[c0+8+i][r]; }
    *(u16x8*)(op)     = v0;
    *(u16x8*)(op + 8) = v1;
}

// -------- fused chunked scan: block = (b,d), 4 waves ----------------
__global__ __launch_bounds__(256) void scan_fused2(
    const float* __restrict__ dtT, const __bf16* __restrict__ xcT,
    const __bf16* __restrict__ zT, const float* __restrict__ dbl,
    const float* __restrict__ A_log, const float* __restrict__ Dp,
    __bf16* __restrict__ yT)
{
    __shared__ float Pa[12][NST];
    __shared__ float Ha[12][NST];
    __shared__ float Ys[4][64];
    const int w = threadIdx.x >> 6;
    const int lane = threadIdx.x & 63;
    const int d = blockIdx.x & (DI - 1);
    const int b = blockIdx.x >> 9;
    const float An2 = -__expf(A_log[d * NST + lane]) * 1.44269504f;
    const float dpd = Dp[d];
    const size_t rowb = (size_t)b * LSEQ;
    const size_t tixb = (size_t)d * ROWS + rowb;

    // ---- phase 1 ----
    #pragma unroll 1
    for (int cc = 0; cc < 3; ++cc) {
        const int c = w * 3 + cc;
        const size_t tix = tixb + (size_t)c * CL;
        float dtv = dtT[tix + lane];
        float uvf = (float)xcT[tix + lane];
        float duv = dtv * uvf;
        float Sdt = dtv;
        #pragma unroll
        for (int o = 32; o; o >>= 1) Sdt += __shfl_xor(Sdt, o, 64);
        const float* bp = dbl + (rowb + (size_t)c * CL) * 144 + 16 + lane;
        float H = 0.f;
        #pragma unroll
        for (int j = 0; j < 8; ++j) {
            #pragma unroll
            for (int q = 0; q < 8; ++q) {
                const int t = 8*j + q;
                float dA = fexp2(rlane(dtv, t) * An2);
                H = fmaf(dA, H, rlane(duv, t) * bp[q * 144]);
            }
            bp += 8 * 144;
        }
        Pa[c][lane] = fexp2(An2 * Sdt);
        Ha[c][lane] = H;
    }
    __syncthreads();

    // ---- seed for chunk 4w: chain chunks 0..4w-1 ----
    float h = 0.f;
    #pragma unroll 1
    for (int j = 0; j < w * 4; ++j)
        h = fmaf(Pa[j][lane], h, Ha[j][lane]);

    // ---- phase 2: seeded scan + y ----
    #pragma unroll 1
    for (int cc = 0; cc < 4; ++cc) {
        const int c = w * 4 + cc;
        const size_t tix = tixb + (size_t)c * CL;
        float dtv = dtT[tix + lane];
        float uvf = (float)xcT[tix + lane];
        float zvf = (float)zT[tix + lane];
        float duv = dtv * uvf;
        float gD  = uvf * dpd;
        float wz  = siluf(zvf);
        const float* bp = dbl + (rowb + (size_t)c * CL) * 144 + 16 + lane;
        const float* cp = bp + 64;
        float yred[8];
        #pragma unroll
        for (int j = 0; j < 8; ++j) {
            float s[8];
            #pragma unroll
            for (int q = 0; q < 8; ++q) {
                const int t = 8*j + q;
                float dA = fexp2(rlane(dtv, t) * An2);
                h = fmaf(dA, h, rlane(duv, t) * bp[q * 144]);
                s[q] = h * cp[q * 144];
            }
            yred[j] = tree8(s, lane);
            bp += 8 * 144;
            cp += 8 * 144;
        }
        if ((lane & 7) == 0) {
            #pragma unroll
            for (int j = 0; j < 8; ++j) Ys[w][8*j + (lane >> 3)] = yred[j];
        }
        float y = (Ys[w][lane] + gD) * wz;
        yT[tix + lane] = (__bf16)y;
    }
}

extern "C" void kernel_launch(void* const* d_in, const int* in_sizes, int n_in,
                              void* d_out, int out_size, void* d_ws, size_t ws_size,
                              hipStream_t stream)
{
    const float* x      = (const float*)d_in[0];
    const float* ln_g   = (const float*)d_in[1];
    const float* ln_b   = (const float*)d_in[2];
    const float* in_w   = (const float*)d_in[3];
    const float* conv_w = (const float*)d_in[4];
    const float* conv_b = (const float*)d_in[5];
    const float* xp_w   = (const float*)d_in[6];
    const float* dt_w   = (const float*)d_in[7];
    const float* dt_b   = (const float*)d_in[8];
    const float* A_log  = (const float*)d_in[9];
    const float* Dp     = (const float*)d_in[10];
    const float* out_w  = (const float*)d_in[11];
    float* out = (float*)d_out;

    char* ws = (char*)d_ws;
    const size_t MB = 1u << 20;
    __bf16* xmb  = (__bf16*)(ws + 0*MB);   // in_proj x-branch bf16; dead after conv_tr
    float*  dtT  = (float*)(ws + 8*MB);    // [512][4096] fp32
    __bf16* xcbf = (__bf16*)(ws + 16*MB);  // conv out [4096][512]; dead after x_proj
    __bf16* yTb  = (__bf16*)(ws + 16*MB);  //   then scan out [512][4096]
    __bf16* xcT  = (__bf16*)(ws + 20*MB);  // [512][4096]
    __bf16* zbf  = (__bf16*)(ws + 24*MB);  // in_proj z; dead after conv_tr
    __bf16* ybf  = (__bf16*)(ws + 24*MB);  //   then y re-transposed [4096][512]
    __bf16* zT   = (__bf16*)(ws + 28*MB);  // [512][4096]
    float*  dblb = (float*)(ws + 40*MB);   // 2.25 MB
    __bf16* xnb  = (__bf16*)(ws + 43*MB);  // LN out (2 MB)
    __bf16* w_in  = (__bf16*)(ws + 45*MB);
    __bf16* w_xp  = (__bf16*)(ws + 46*MB);
    __bf16* w_out = (__bf16*)(ws + 46*MB + 512*1024);

    const int na = 2*1024*DM, nb = 2*144*DI, nc = 2*DM*DI;
    f2bf3<<<(na+nb+nc)/1024, 256, 0, stream>>>(
        in_w, w_in, na, xp_w, w_xp, nb, out_w, w_out, nc);

    for (int l = 0; l < 2; ++l) {
        const float* xin = (l == 0) ? x : out;
        ln_kernel<<<ROWS/4, 256, 0, stream>>>(xin, ln_g + l*DM, ln_b + l*DM, xnb);
        // in_proj -> xmb bf16 | z bf16
        gemm_mfma<DM><<<dim3(1024/64, ROWS/64), 256, 0, stream>>>(
            xnb, w_in + (size_t)l*1024*DM, nullptr, xmb, zbf, nullptr, 1024, 1);
        // fused conv+silu (dual layout) + z transpose
        conv_tr_kernel<<<dim3(DI/64, ROWS/64), 256, 0, stream>>>(
            xmb, conv_w + (size_t)l*DI*4, conv_b + (size_t)l*DI,
            (const u16*)zbf, xcbf, (u16*)xcT, (u16*)zT);
        // x_proj -> dbl fp32
        gemm_mfma<DI><<<dim3(3, ROWS/64), 256, 0, stream>>>(
            xcbf, w_xp + (size_t)l*144*DI, dblb, nullptr, nullptr, nullptr, 144, 0);
        // dt projection, transposed fp32 out + softplus (coalesced)
        gemm_dt<<<dim3(DI/64, ROWS/64), 256, 0, stream>>>(
            dblb, 144, dt_w + (size_t)l*DI*16, dtT, dt_b + (size_t)l*DI);
        // fused chunked scan (p1 + carry + p2 in one launch)
        scan_fused2<<<BB*DI, 256, 0, stream>>>(
            dtT, xcT, zT, dblb, A_log + (size_t)l*DI*NST, Dp + (size_t)l*DI, yTb);
        transpose_bf<<<dim3(ROWS/64, DI/64), 256, 0, stream>>>(
            (const u16*)yTb, (u16*)ybf, ROWS, DI);
        // out_proj + residual
        gemm_mfma<DI><<<dim3(DM/64, ROWS/64), 256, 0, stream>>>(
            ybf, w_out + (size_t)l*DM*DI, out, nullptr, nullptr, xin, DM, 2);
    }
}